// Round 11
// baseline (3796.400 us; speedup 1.0000x reference)
//
#include <hip/hip_runtime.h>
#include <hip/hip_fp16.h>
#include <stdint.h>

typedef _Float16 half8 __attribute__((ext_vector_type(8)));
typedef float f32x4 __attribute__((ext_vector_type(4)));
typedef unsigned long long ull;

__device__ __forceinline__ uint16_t f2h(float f) {
    __half h = __float2half(f);
    return *reinterpret_cast<uint16_t*>(&h);
}
__device__ __forceinline__ float h2f(uint16_t b) {
    return (float)__builtin_bit_cast(_Float16, b);
}
__device__ __forceinline__ uint32_t pk2(float lo, float hi) {
    return (uint32_t)f2h(lo) | ((uint32_t)f2h(hi) << 16);
}
__device__ __forceinline__ float sigm(float v) {
    return __builtin_amdgcn_rcpf(1.f + __expf(-v));
}
__device__ __forceinline__ float tanhfast(float v) {
    float e = __expf(2.f * v);
    return 1.f - 2.f * __builtin_amdgcn_rcpf(e + 1.f);
}

// xg layout: ull per (grp, t, gu, m): idx = ((grp*1024 + t)*256 + gu)*16 + m
// ull = 4 gates f16: f | i<<16 | o<<32 | g<<48.  Total 268,435,456 B in d_ws.
// (r10 proved ws_size >= 268.7 MB: its fast path ran.)

// ---- phase 1: xg[b,t,col] = x[b,t,:]@wx[:,col] + bias (r10-verified core,
//      only the output index changed). grid 256 = tchunk16 x grp8 x slice2.
__global__ __launch_bounds__(512, 1) void xw_gemm(
    const float* __restrict__ x, const float* __restrict__ wx,
    const float* __restrict__ bias, ull* __restrict__ xg)
{
    const int tid = threadIdx.x;
    const int tc = blockIdx.x >> 4;
    const int grp = (blockIdx.x >> 1) & 7;
    const int slice = blockIdx.x & 1;
    const int lane = tid & 63, wave = tid >> 6;
    const int cw = lane & 15, lhi = lane >> 4;
    const int u = wave * 16 + cw;

    __shared__ __align__(16) uint16_t Wxl[512 * 136];       // 139264 B
    __shared__ __align__(16) uint16_t Xl[2][16][33][8];     // 16896 B

    half8 Wxf[4][8];
    #pragma unroll
    for (int p = 0; p < 2; ++p) {
        for (int idx = tid; idx < 512 * 128; idx += 512) {
            int k_l = idx >> 9, c_l = idx & 511;
            int gg = c_l >> 7, uu = c_l & 127;
            int col = gg * 256 + slice * 128 + uu;
            Wxl[c_l * 136 + k_l] = f2h(wx[(size_t)(p * 128 + k_l) * 1024 + col]);
        }
        __syncthreads();
        #pragma unroll
        for (int g = 0; g < 4; ++g)
            #pragma unroll
            for (int jj = 0; jj < 4; ++jj)
                Wxf[g][p * 4 + jj] = *reinterpret_cast<const half8*>(
                    &Wxl[(g * 128 + u) * 136 + jj * 32 + lhi * 8]);
        __syncthreads();
    }
    float bv[4];
    #pragma unroll
    for (int g = 0; g < 4; ++g) bv[g] = bias[g * 256 + slice * 128 + u];

    const int t0 = tc * 64;
    const int m_s = tid >> 5, q_s = tid & 31;
    const float* xrow = &x[((size_t)(grp * 16 + m_s) * 1024) * 256 + q_s * 8];
    {
        const float4* xs = reinterpret_cast<const float4*>(xrow + (size_t)t0 * 256);
        float4 a = xs[0], b = xs[1];
        uint4 pkv = {pk2(a.x, a.y), pk2(a.z, a.w), pk2(b.x, b.y), pk2(b.z, b.w)};
        *reinterpret_cast<uint4*>(&Xl[0][m_s][q_s][0]) = pkv;
    }
    float4 xa, xb;
    {
        const float4* xs = reinterpret_cast<const float4*>(xrow + (size_t)(t0 + 1) * 256);
        xa = xs[0]; xb = xs[1];
    }
    __syncthreads();

    for (int tt = 0; tt < 64; ++tt) {
        const int t = t0 + tt, buf = tt & 1, bn = buf ^ 1;
        if (tt < 63) {
            uint4 pkv = {pk2(xa.x, xa.y), pk2(xa.z, xa.w), pk2(xb.x, xb.y), pk2(xb.z, xb.w)};
            *reinterpret_cast<uint4*>(&Xl[bn][m_s][q_s][0]) = pkv;
        }
        if (tt < 62) {
            const float4* xs = reinterpret_cast<const float4*>(xrow + (size_t)(t + 2) * 256);
            xa = xs[0]; xb = xs[1];
        }
        f32x4 a0 = {0,0,0,0}, a1 = {0,0,0,0}, a2 = {0,0,0,0}, a3 = {0,0,0,0};
        #pragma unroll
        for (int ks = 0; ks < 8; ++ks) {
            half8 av = *reinterpret_cast<const half8*>(&Xl[buf][cw][ks * 4 + lhi][0]);
            a0 = __builtin_amdgcn_mfma_f32_16x16x32_f16(av, Wxf[0][ks], a0, 0, 0, 0);
            a1 = __builtin_amdgcn_mfma_f32_16x16x32_f16(av, Wxf[1][ks], a1, 0, 0, 0);
            a2 = __builtin_amdgcn_mfma_f32_16x16x32_f16(av, Wxf[2][ks], a2, 0, 0, 0);
            a3 = __builtin_amdgcn_mfma_f32_16x16x32_f16(av, Wxf[3][ks], a3, 0, 0, 0);
        }
        #pragma unroll
        for (int r = 0; r < 4; ++r) {
            ull v = (ull)f2h(a0[r] + bv[0])
                  | ((ull)f2h(a1[r] + bv[1]) << 16)
                  | ((ull)f2h(a2[r] + bv[2]) << 32)
                  | ((ull)f2h(a3[r] + bv[3]) << 48);
            xg[(((size_t)(grp * 1024 + t) * 256) + slice * 128 + u) * 16 + lhi * 4 + r] = v;
        }
        __syncthreads();
    }
}

// ---- phase 2: recurrence. grid 8 (one block per 16-batch group), 512 thr.
// Wave w owns units [w*32, w*32+32) x 4 gates = 128 cols.
// Tile j = g*2+q: cols g*256 + w*32 + q*16 + cw.  B-frags: 48 in regs, 16 in LDS.
// State (m = lhi*4+r, u = w*32+q*16+cw): all 4 gates in-lane, 8 states/lane.
__global__ __launch_bounds__(512, 2) void lstm_rec(
    const float* __restrict__ h0, const float* __restrict__ c0,
    const float* __restrict__ wh, float* __restrict__ out,
    const ull* __restrict__ xg)
{
    const int tid = threadIdx.x;
    const int grp = blockIdx.x;           // 0..7
    const int lane = tid & 63, w = tid >> 6;
    const int cw = lane & 15, lhi = lane >> 4;

    __shared__ __align__(16) uint16_t Wlds[8][8][2][64][8];  // 128 KB (kt 6,7)
    __shared__ __align__(16) uint16_t Hs[2][16][32][8];      // 16 KB dbuf, slot^(m&7)

    // ---- prologue: weights straight from global (one-time, L2/L3-served) ----
    half8 Wf[48];                          // Wf[j*6 + kt], kt 0..5
    #pragma unroll
    for (int j = 0; j < 8; ++j) {
        const int col = (j >> 1) * 256 + w * 32 + (j & 1) * 16 + cw;
        #pragma unroll
        for (int kt = 0; kt < 8; ++kt) {
            const int kbase = kt * 32 + lhi * 8;
            half8 f;
            #pragma unroll
            for (int e = 0; e < 8; ++e)
                f[e] = (_Float16)wh[(size_t)(kbase + e) * 1024 + col];
            if (kt < 6) Wf[j * 6 + kt] = f;
            else *reinterpret_cast<half8*>(&Wlds[w][j][kt - 6][lane][0]) = f;
        }
    }

    // ---- h0 -> Hs[0], c0 -> regs; xg(t=0) prefetch ----
    float c8[8], hv8[8];
    #pragma unroll
    for (int q = 0; q < 2; ++q)
        #pragma unroll
        for (int r = 0; r < 4; ++r) {
            int m = lhi * 4 + r, u = w * 32 + q * 16 + cw;
            c8[q * 4 + r] = c0[(size_t)(grp * 16 + m) * 256 + u];
            Hs[0][m][(u >> 3) ^ (m & 7)][u & 7] =
                f2h(h0[(size_t)(grp * 16 + m) * 256 + u]);
        }
    const ull* xgb = xg + (size_t)grp * 1024 * 4096;   // 4096 ull per t
    const int u0 = w * 32 + cw;
    ull xq[8];
    #pragma unroll
    for (int q = 0; q < 2; ++q)
        #pragma unroll
        for (int r = 0; r < 4; ++r)
            xq[q * 4 + r] = xgb[(size_t)(u0 + q * 16) * 16 + lhi * 4 + r];
    __syncthreads();

    // ---- time loop: ONE barrier per step ----
    for (int t = 0; t < 1024; ++t) {
        const int par = t & 1, pn = par ^ 1;

        // acc init = xg (x@wx + bias), then free xq for the next prefetch
        f32x4 acc[8];
        #pragma unroll
        for (int j = 0; j < 8; ++j) {
            const int q = j & 1, g = j >> 1;
            #pragma unroll
            for (int r = 0; r < 4; ++r)
                acc[j][r] = h2f((uint16_t)(xq[q * 4 + r] >> (16 * g)));
        }
        {   // prefetch xg(t+1): one full step of latency cover
            int tn = (t + 1 < 1024) ? t + 1 : t;
            const ull* p = xgb + (size_t)tn * 4096;
            #pragma unroll
            for (int q = 0; q < 2; ++q)
                #pragma unroll
                for (int r = 0; r < 4; ++r)
                    xq[q * 4 + r] = p[(size_t)(u0 + q * 16) * 16 + lhi * 4 + r];
        }

        // hGEMM: 8 k-tiles x 8 col-tiles; A from LDS, B from regs (kt<6) or LDS
        #pragma unroll
        for (int kt = 0; kt < 8; ++kt) {
            half8 A = *reinterpret_cast<const half8*>(
                &Hs[par][cw][(kt * 4 + lhi) ^ (cw & 7)][0]);
            if (kt < 6) {
                #pragma unroll
                for (int j = 0; j < 8; ++j)
                    acc[j] = __builtin_amdgcn_mfma_f32_16x16x32_f16(
                        A, Wf[j * 6 + kt], acc[j], 0, 0, 0);
            } else {
                #pragma unroll
                for (int j = 0; j < 8; ++j) {
                    half8 B = *reinterpret_cast<const half8*>(
                        &Wlds[w][j][kt - 6][lane][0]);
                    acc[j] = __builtin_amdgcn_mfma_f32_16x16x32_f16(
                        A, B, acc[j], 0, 0, 0);
                }
            }
        }

        // gates + state update: 8 complete states per lane, zero shuffles
        #pragma unroll
        for (int q = 0; q < 2; ++q)
            #pragma unroll
            for (int r = 0; r < 4; ++r) {
                const int s = q * 4 + r;
                float fg = sigm(acc[0 + q][r]);        // j = 0*2+q
                float ig = sigm(acc[2 + q][r]);        // j = 1*2+q
                float og = sigm(acc[4 + q][r]);        // j = 2*2+q
                float gv = tanhfast(acc[6 + q][r]);    // j = 3*2+q
                c8[s] = fmaf(c8[s], fg, gv * ig);
                hv8[s] = tanhfast(c8[s]) * og;
            }

        // write h(t+1) into the other Hs buffer + fullh to global
        #pragma unroll
        for (int q = 0; q < 2; ++q)
            #pragma unroll
            for (int r = 0; r < 4; ++r) {
                int m = lhi * 4 + r, u = w * 32 + q * 16 + cw;
                Hs[pn][m][(u >> 3) ^ (m & 7)][u & 7] = f2h(hv8[q * 4 + r]);
                out[((size_t)(grp * 16 + m) * 1024 + t) * 256 + u] = hv8[q * 4 + r];
            }
        __syncthreads();   // new h staged for every wave; old buffer reusable
    }

    // ---- finals: h_f, c_f ----
    const size_t fsz = (size_t)128 * 1024 * 256;
    #pragma unroll
    for (int q = 0; q < 2; ++q)
        #pragma unroll
        for (int r = 0; r < 4; ++r) {
            int m = lhi * 4 + r, u = w * 32 + q * 16 + cw;
            int b = grp * 16 + m;
            out[fsz + (size_t)b * 256 + u] = hv8[q * 4 + r];
            out[fsz + (size_t)128 * 256 + (size_t)b * 256 + u] = c8[q * 4 + r];
        }
}

extern "C" void kernel_launch(void* const* d_in, const int* in_sizes, int n_in,
                              void* d_out, int out_size, void* d_ws, size_t ws_size,
                              hipStream_t stream) {
    const float* x    = (const float*)d_in[0];
    const float* h0   = (const float*)d_in[1];
    const float* c0   = (const float*)d_in[2];
    const float* wx   = (const float*)d_in[3];
    const float* wh   = (const float*)d_in[4];
    const float* bias = (const float*)d_in[5];
    float* out = (float*)d_out;
    ull* xgp = (ull*)d_ws;   // fully overwritten by xw_gemm each call: replay-safe

    xw_gemm<<<256, 512, 0, stream>>>(x, wx, bias, xgp);
    lstm_rec<<<8, 512, 0, stream>>>(h0, c0, wh, out, xgp);
}